// Round 5
// baseline (90.051 us; speedup 1.0000x reference)
//
#include <hip/hip_runtime.h>
#include <cstddef>
#include <cstdint>

// Problem constants (from reference setup_inputs)
#define T_DIM 500
#define B_DIM 32
#define C_DIM 1024
#define O_DIM 1024
#define M_DIM (T_DIM * B_DIM)   // 16000
#define MP_DIM 16128            // padded to 63*256
#define BO_DIM (B_DIM * O_DIM)  // 32768

typedef __attribute__((ext_vector_type(8))) short bf16x8;
typedef __attribute__((ext_vector_type(4))) float f32x4;

static __device__ __forceinline__ ushort f2bf(float x) {
  unsigned u = __float_as_uint(x);
  return (ushort)((u + 0x7FFF + ((u >> 16) & 1)) >> 16);  // RNE
}
static __device__ __forceinline__ float bf2f(ushort u) {
  return __uint_as_float(((unsigned)u) << 16);
}

// Inline-asm ds_read_b128: invisible to the compiler's vmem-dependency
// tracking, so it cannot insert s_waitcnt vmcnt(0) drains for the outstanding
// global_load_lds ops (the m97-style pipeline flattener). Ordering vs
// barriers: volatile asm does not move across side-effecting intrinsics.
static __device__ __forceinline__ bf16x8 ldsr(const ushort* p) {
  bf16x8 d;
  asm volatile("ds_read_b128 %0, %1"
               : "=v"(d)
               : "v"((unsigned)(uintptr_t)(const __attribute__((address_space(3))) ushort*)p));
  return d;
}

// ---------------------------------------------------------------------------
// K0: transpose + cast x[B, C, T] fp32 -> xt[(t*B + b), c] bf16 ([MP, C])
// ---------------------------------------------------------------------------
__global__ __launch_bounds__(256) void k_transpose(const float* __restrict__ x,
                                                   ushort* __restrict__ xt) {
  __shared__ float tile[32][33];
  const int b  = blockIdx.z;
  const int t0 = blockIdx.x * 32;
  const int c0 = blockIdx.y * 32;
  const int tx = threadIdx.x;      // 0..31
  const int ty = threadIdx.y;      // 0..7

  const int t = t0 + tx;
  if (t < T_DIM) {
#pragma unroll
    for (int r = 0; r < 4; ++r) {
      const int c = c0 + ty + r * 8;
      tile[ty + r * 8][tx] = x[((size_t)b * C_DIM + c) * T_DIM + t];
    }
  }
  __syncthreads();
#pragma unroll
  for (int r = 0; r < 4; ++r) {
    const int tt = t0 + ty + r * 8;
    if (tt < T_DIM) {
      xt[((size_t)tt * B_DIM + b) * C_DIM + c0 + tx] = f2bf(tile[tx][ty + r * 8]);
    }
  }
}

// ---------------------------------------------------------------------------
// KW: cast W[O, C] fp32 -> bf16
// ---------------------------------------------------------------------------
__global__ __launch_bounds__(256) void k_cast_w(const float4* __restrict__ W,
                                                ushort* __restrict__ Wb) {
  const int i = blockIdx.x * 256 + threadIdx.x;   // over O*C/4
  const float4 w = W[i];
  ushort* o = Wb + (size_t)i * 4;
  o[0] = f2bf(w.x); o[1] = f2bf(w.y); o[2] = f2bf(w.z); o[3] = f2bf(w.w);
}

// ---------------------------------------------------------------------------
// K1: bf16 MFMA GEMM (NT): v[MP, O] = xt[MP, K] * Wb[O, K]^T, bf16 out.
// 256x256 tile, BK=64, 8 waves, 2-slot LDS ring, 4 phases/K-tile, counted
// vmcnt (asm), inline-asm ds_read_b128 fragment loads (no compiler drains),
// involution k-swizzle (verified 0 bank conflicts), setprio on MFMA clusters.
//
// Race-freedom (unchanged from R4, verified absmax=0):
//  - ph1 opens with per-wave vmcnt(8) [only tile t+1's 8 loads may remain
//    outstanding] + barrier => tile t fully landed for all waves.
//  - ph1+ph2 issue ALL ds_reads of slot s; ph2 ends lgkmcnt(0)+barrier =>
//    slot s fully consumed before ph3/ph4 stage tile t+2 into it.
//  - t==15: nothing newer outstanding => vmcnt(0) (fixes vacuous vmcnt(8)).
// ---------------------------------------------------------------------------
__global__ __launch_bounds__(512, 2) void k_gemm_bf16(const ushort* __restrict__ A,
                                                      const ushort* __restrict__ Bw,
                                                      ushort* __restrict__ C) {
  // [slot:2][mat:2(A,B)][rowhalf:2][khalf:2][r:128][k:32] bf16, swizzled k
  __shared__ ushort lds[65536];  // 128 KiB

  const int tid  = threadIdx.x;
  const int wid  = tid >> 6;       // 0..7
  const int lane = tid & 63;

  // bijective XCD chunk swizzle (m204): nwg=252, q=31, r=4
  const int orig = blockIdx.x;
  const int xcd  = orig & 7;
  const int base = (xcd < 4) ? xcd * 32 : 128 + (xcd - 4) * 31;
  const int wgid = base + (orig >> 3);
  const int row0 = (wgid >> 2) * 256;   // 63 row tiles (col-fast => A L2 reuse)
  const int col0 = (wgid & 3) * 256;    // 4 col tiles

  const int wm = wid >> 2;         // 0..1 : wave row-half
  const int wn = wid & 3;          // 0..3 : wave col-quarter

  f32x4 acc[8][4] = {};            // [m-frag][n-frag]

  // ---- staging source addresses (pre-swizzled k so LDS lands swizzled) ----
  const int srow = wid * 16 + (lane >> 2);
  const int skof = ((lane & 3) * 8) ^ (((lane >> 5) & 1) << 4);
  const ushort* Abase = A  + (size_t)(row0 + srow) * C_DIM + skof;
  const ushort* Bbase = Bw + (size_t)(col0 + srow) * C_DIM + skof;

  // ---- fragment read offsets (matching involution) ----
  const int fr  = lane & 15;
  const int fko = ((lane >> 4) * 8) ^ (((lane >> 3) & 1) << 4);
  const int aoff = wm * 8192 + fr * 32 + fko;                                   // + h*4096 + i*512
  const int boff = 16384 + (wn >> 1) * 8192 + (wn & 1) * 2048 + fr * 32 + fko;  // + h*4096 + j*512

#define STAGE_A(K0S, SB)                                                          \
  _Pragma("unroll")                                                               \
  for (int rh = 0; rh < 2; ++rh)                                                  \
    _Pragma("unroll")                                                             \
    for (int kh = 0; kh < 2; ++kh)                                                \
      __builtin_amdgcn_global_load_lds(                                           \
          (const __attribute__((address_space(1))) void*)(Abase + (size_t)rh * 128 * C_DIM + (K0S) + kh * 32), \
          (__attribute__((address_space(3))) void*)&lds[(SB) + rh * 8192 + kh * 4096 + wid * 512], 16, 0, 0)

#define STAGE_B(K0S, SB)                                                          \
  _Pragma("unroll")                                                               \
  for (int rh = 0; rh < 2; ++rh)                                                  \
    _Pragma("unroll")                                                             \
    for (int kh = 0; kh < 2; ++kh)                                                \
      __builtin_amdgcn_global_load_lds(                                           \
          (const __attribute__((address_space(1))) void*)(Bbase + (size_t)rh * 128 * C_DIM + (K0S) + kh * 32), \
          (__attribute__((address_space(3))) void*)&lds[(SB) + 16384 + rh * 8192 + kh * 4096 + wid * 512], 16, 0, 0)

  // prologue: stage tiles 0 and 1
  STAGE_A(0, 0);
  STAGE_B(0, 0);
  STAGE_A(64, 32768);
  STAGE_B(64, 32768);

  for (int t = 0; t < 16; ++t) {
    const int sb = (t & 1) * 32768;
    bf16x8 a0[4][2], a1[4][2], b0[2][2], b1[2][2];

    // ---------- ph1: frags (a0, b0); MFMA quad (i0-3 x j0-1) ----------
    if (t < 15) { asm volatile("s_waitcnt vmcnt(8)" ::: "memory"); }
    else        { asm volatile("s_waitcnt vmcnt(0)" ::: "memory"); }
    __builtin_amdgcn_s_barrier();                      // tile t landed, all waves
#pragma unroll
    for (int i = 0; i < 4; ++i)
#pragma unroll
      for (int h = 0; h < 2; ++h)
        a0[i][h] = ldsr(&lds[sb + aoff + h * 4096 + i * 512]);
#pragma unroll
    for (int j = 0; j < 2; ++j)
#pragma unroll
      for (int h = 0; h < 2; ++h)
        b0[j][h] = ldsr(&lds[sb + boff + h * 4096 + j * 512]);
    asm volatile("s_waitcnt lgkmcnt(0)" ::: "memory");
    __builtin_amdgcn_sched_barrier(0);
    __builtin_amdgcn_s_setprio(1);
#pragma unroll
    for (int i = 0; i < 4; ++i)
#pragma unroll
      for (int j = 0; j < 2; ++j)
#pragma unroll
        for (int h = 0; h < 2; ++h)
          acc[i][j] = __builtin_amdgcn_mfma_f32_16x16x32_bf16(a0[i][h], b0[j][h], acc[i][j], 0, 0, 0);
    __builtin_amdgcn_s_setprio(0);
    __builtin_amdgcn_s_barrier();

    // ---------- ph2: frags (a1, b1); MFMA quad (i4-7 x j0-1) ----------
#pragma unroll
    for (int i = 0; i < 4; ++i)
#pragma unroll
      for (int h = 0; h < 2; ++h)
        a1[i][h] = ldsr(&lds[sb + aoff + h * 4096 + (4 + i) * 512]);
#pragma unroll
    for (int j = 0; j < 2; ++j)
#pragma unroll
      for (int h = 0; h < 2; ++h)
        b1[j][h] = ldsr(&lds[sb + boff + h * 4096 + (2 + j) * 512]);
    asm volatile("s_waitcnt lgkmcnt(0)" ::: "memory");
    __builtin_amdgcn_sched_barrier(0);
    __builtin_amdgcn_s_setprio(1);
#pragma unroll
    for (int i = 0; i < 4; ++i)
#pragma unroll
      for (int j = 0; j < 2; ++j)
#pragma unroll
        for (int h = 0; h < 2; ++h)
          acc[4 + i][j] = __builtin_amdgcn_mfma_f32_16x16x32_bf16(a1[i][h], b0[j][h], acc[4 + i][j], 0, 0, 0);
    __builtin_amdgcn_s_setprio(0);
    __builtin_amdgcn_s_barrier();          // ALL slot reads for tile t done

    // ---------- ph3: stage A(t+2) into this slot; MFMA (i0-3 x j2-3) ------
    if (t < 14) { STAGE_A((t + 2) * 64, sb); }
    __builtin_amdgcn_s_setprio(1);
#pragma unroll
    for (int i = 0; i < 4; ++i)
#pragma unroll
      for (int j = 0; j < 2; ++j)
#pragma unroll
        for (int h = 0; h < 2; ++h)
          acc[i][2 + j] = __builtin_amdgcn_mfma_f32_16x16x32_bf16(a0[i][h], b1[j][h], acc[i][2 + j], 0, 0, 0);
    __builtin_amdgcn_s_setprio(0);
    __builtin_amdgcn_s_barrier();

    // ---------- ph4: stage B(t+2); MFMA (i4-7 x j2-3) ---------------------
    if (t < 14) { STAGE_B((t + 2) * 64, sb); }
    __builtin_amdgcn_s_setprio(1);
#pragma unroll
    for (int i = 0; i < 4; ++i)
#pragma unroll
      for (int j = 0; j < 2; ++j)
#pragma unroll
        for (int h = 0; h < 2; ++h)
          acc[4 + i][2 + j] = __builtin_amdgcn_mfma_f32_16x16x32_bf16(a1[i][h], b1[j][h], acc[4 + i][2 + j], 0, 0, 0);
    __builtin_amdgcn_s_setprio(0);
    __builtin_amdgcn_s_barrier();
  }

  // epilogue: C/D layout col = lane&15, row = (lane>>4)*4 + reg  [m89]
  const int crow = (lane >> 4) * 4;
  const int ccol = lane & 15;
#pragma unroll
  for (int i = 0; i < 8; ++i)
#pragma unroll
    for (int j = 0; j < 4; ++j) {
      ushort* cp = C + (size_t)(row0 + wm * 128 + i * 16 + crow) * O_DIM
                     + (col0 + wn * 64 + j * 16 + ccol);
#pragma unroll
      for (int r = 0; r < 4; ++r) cp[(size_t)r * O_DIM] = f2bf(acc[i][j][r]);
    }
#undef STAGE_A
#undef STAGE_B
}

// ---------------------------------------------------------------------------
// K2: fused PSP alpha-filter + refractory spike scan (bf16 v input).
// One thread per (b, o); 64-thr blocks (512 blocks, all CUs); 3-chunk-deep
// register prefetch; static indices only.
// ---------------------------------------------------------------------------
__global__ __launch_bounds__(64) void k_scan(const ushort* __restrict__ v,
                                             float* __restrict__ out) {
  const int g = blockIdx.x * 64 + threadIdx.x;  // b*O + o

  const float a1 = 0.90483741803595952f;   // exp(-TS/TAU_SR)
  const float c1 = 0.27182818284590452f;   // e*TS/TAU_SR
  const float a2 = 0.36787944117144233f;   // exp(-TS/TAU_REF)
  const float c2 = -54.365636569180905f;   // -SCALE_REF*THETA*e*TS/TAU_REF

  float p1 = 0.f, q1 = 0.f;
  float p2 = 0.f, q2 = 0.f;

  const ushort* vp = v + g;
  float* op = out + (size_t)g * T_DIM;

  constexpr int D  = 20;   // t-steps per chunk
  constexpr int NC = 25;   // chunks (D*NC = 500)

  ushort b0[D], b1[D], b2[D];
#pragma unroll
  for (int j = 0; j < D; ++j) b0[j] = vp[(size_t)j * BO_DIM];
#pragma unroll
  for (int j = 0; j < D; ++j) b1[j] = vp[(size_t)(D + j) * BO_DIM];
#pragma unroll
  for (int j = 0; j < D; ++j) b2[j] = vp[(size_t)(2 * D + j) * BO_DIM];

#pragma unroll 5
  for (int c = 0; c < NC; ++c) {
    const int cn = (c + 3 < NC) ? (c + 3) : (NC - 1);
    ushort bn[D];
    {
      const size_t base = (size_t)cn * D;
#pragma unroll
      for (int j = 0; j < D; ++j) bn[j] = vp[(base + j) * BO_DIM];
    }

    float rr[D];
#pragma unroll
    for (int j = 0; j < D; ++j) {
      const float vn = bf2f(b0[j]);
      q1 = a1 * q1 + a1 * p1;
      p1 = a1 * p1 + vn;
      const float u = c1 * q1;
      q2 = a2 * q2 + a2 * p2;
      const float s = (u + c2 * q2 >= 10.0f) ? 1.0f : 0.0f;
      p2 = a2 * p2 + s;
      rr[j] = s;
    }

    float* o = op + c * D;
#pragma unroll
    for (int j = 0; j < D; j += 4)
      *(float4*)&o[j] = make_float4(rr[j], rr[j + 1], rr[j + 2], rr[j + 3]);

#pragma unroll
    for (int j = 0; j < D; ++j) { b0[j] = b1[j]; b1[j] = b2[j]; b2[j] = bn[j]; }
  }
}

// ---------------------------------------------------------------------------
extern "C" void kernel_launch(void* const* d_in, const int* in_sizes, int n_in,
                              void* d_out, int out_size, void* d_ws, size_t ws_size,
                              hipStream_t stream) {
  const float* x = (const float*)d_in[0];  // [B, C, 1, 1, T] fp32 (binary)
  const float* W = (const float*)d_in[1];  // [O, C] fp32
  float* out = (float*)d_out;              // [B, O, 1, 1, T] fp32

  ushort* v  = (ushort*)d_ws;                         // [MP, O] bf16, 33 MB
  ushort* xt = v + (size_t)MP_DIM * O_DIM;            // [MP, C] bf16, 33 MB
  ushort* Wb = xt + (size_t)MP_DIM * C_DIM;           // [O, C] bf16, 2 MB

  // K0: transpose + cast
  dim3 g0((T_DIM + 31) / 32, C_DIM / 32, B_DIM);
  k_transpose<<<g0, dim3(32, 8), 0, stream>>>(x, xt);

  // KW: cast W to bf16
  k_cast_w<<<(O_DIM * C_DIM / 4) / 256, 256, 0, stream>>>((const float4*)W, Wb);

  // K1: v = xt * Wb^T  (256^2 tile, 4-phase counted-vmcnt schedule, asm reads)
  k_gemm_bf16<<<(MP_DIM / 256) * (O_DIM / 256), 512, 0, stream>>>(xt, Wb, v);

  // K2: fused filter + spike scan
  k_scan<<<BO_DIM / 64, 64, 0, stream>>>(v, out);
}